// Round 6
// baseline (103.224 us; speedup 1.0000x reference)
//
#include <hip/hip_runtime.h>
#include <math.h>

// features: (1,50,50,1024) fp32 NHWC; boxes: (1,300,4) [y1,x1,y2,x2] in [0,1]
// CROP=14, POOL_K=2 -> out (1,300,7,7,1024) fp32
#define FH 50
#define FW 50
#define FC 1024
#define FC4 256        // float4s per pixel (fp32) == uint2s per pixel (bf16)
#define NBOX 300
#define PO 7
#define NCELL (PO * PO)          // 49
#define CHQ 4                    // channel quarters (64 thr x 4ch = 256 ch)
#define BPB (NCELL * CHQ)        // blocks per box = 196
#define NPIX (FH * FW * FC)      // 2,560,000 elements
#define BF16_BYTES (NPIX * 2)    // 5,242,880

typedef float nat4 __attribute__((ext_vector_type(4)));

__device__ __forceinline__ nat4 lerp4(nat4 a, nat4 b, float w) {
    return a + (b - a) * w;
}
__device__ __forceinline__ nat4 max4(nat4 a, nat4 b) {
    nat4 r;
    r.x = fmaxf(a.x, b.x);
    r.y = fmaxf(a.y, b.y);
    r.z = fmaxf(a.z, b.z);
    r.w = fmaxf(a.w, b.w);
    return r;
}
// unpack 4 bf16 channels (packed little-endian in uint2) to f32
__device__ __forceinline__ nat4 bf2f(uint2 u) {
    nat4 r;
    r.x = __uint_as_float(u.x << 16);
    r.y = __uint_as_float(u.x & 0xffff0000u);
    r.z = __uint_as_float(u.y << 16);
    r.w = __uint_as_float(u.y & 0xffff0000u);
    return r;
}
__device__ __forceinline__ unsigned bfpack(float a, float b) {  // RNE to bf16
    unsigned ua = __float_as_uint(a);
    unsigned ub = __float_as_uint(b);
    ua += 0x7fffu + ((ua >> 16) & 1u);
    ub += 0x7fffu + ((ub >> 16) & 1u);
    return (ua >> 16) | (ub & 0xffff0000u);
}

// Pass 1: fp32 features -> bf16 in workspace (15 MB traffic, ~3 us).
__global__ __launch_bounds__(256) void cvt_kernel(
    const float* __restrict__ feat, unsigned* __restrict__ ws)
{
    const int i = blockIdx.x * 256 + threadIdx.x;   // float4 index, 640,000 total
    const float4 v = reinterpret_cast<const float4*>(feat)[i];
    uint2 w;
    w.x = bfpack(v.x, v.y);
    w.y = bfpack(v.z, v.w);
    reinterpret_cast<uint2*>(ws)[i] = w;
}

// Pass 2: one SINGLE-WAVE block per (box, pooled cell, channel quarter).
// 16 INDEPENDENT bf16 dwordx2 loads per wave (full MLP, one vmcnt drain),
// bilinear in f32, 2x2 max, one contiguous NT dwordx4 store.
// 58,800 waves of real work -> latency hidden by TLP, no serial rounds.
__global__ __launch_bounds__(64) void roi_pool_bf16_kernel(
    const unsigned* __restrict__ ws,   // bf16 features (50,50,1024)
    const float* __restrict__ boxes,   // (300,4)
    float* __restrict__ out)           // (300,7,7,1024)
{
    const int j = blockIdx.x & 7;              // XCD slot
    const int k = blockIdx.x >> 3;
    const int n = j + 8 * (k / BPB);           // box: box's 196 blocks share XCD
    if (n >= NBOX) return;
    const int rem  = k % BPB;
    const int cell = rem >> 2;                 // 0..48  (py*7+px)
    const int cq   = rem & 3;                  // channel quarter
    const int py   = cell / PO;
    const int px   = cell - py * PO;
    const int c    = cq * 64 + threadIdx.x;    // uint2 index in pixel, 0..255

    // Box coords — block-uniform scalar loads.
    const float by1 = boxes[n * 4 + 0];
    const float bx1 = boxes[n * 4 + 1];
    const float by2 = boxes[n * 4 + 2];
    const float bx2 = boxes[n * 4 + 3];

    const float stepy = (by2 - by1) * (49.0f / 13.0f);
    const float stepx = (bx2 - bx1) * (49.0f / 13.0f);
    const float basey = by1 * 49.0f;
    const float basex = bx1 * 49.0f;

    // Row pair for dy=0 (A) and dy=1 (B); col pair for dx=0 (L) and dx=1 (R).
    const float ysA = basey + (float)(2 * py) * stepy;
    const float ysB = ysA + stepy;
    const float xsL = basex + (float)(2 * px) * stepx;
    const float xsR = xsL + stepx;

    const float fyA = floorf(ysA); const float wyA = ysA - fyA;
    const float fyB = floorf(ysB); const float wyB = ysB - fyB;
    const float fxL = floorf(xsL); const float wxL = xsL - fxL;
    const float fxR = floorf(xsR); const float wxR = xsR - fxR;

    const int y0A = min(max((int)fyA, 0), FH - 1); const int y1A = min(y0A + 1, FH - 1);
    const int y0B = min(max((int)fyB, 0), FH - 1); const int y1B = min(y0B + 1, FH - 1);
    const int x0L = min(max((int)fxL, 0), FW - 1); const int x1L = min(x0L + 1, FW - 1);
    const int x0R = min(max((int)fxR, 0), FW - 1); const int x1R = min(x0R + 1, FW - 1);

    const uint2* __restrict__ f2 = reinterpret_cast<const uint2*>(ws);
    const int ry[4] = { y0A * FW, y1A * FW, y0B * FW, y1B * FW };
    const int cx[4] = { x0L, x1L, x0R, x1R };

    // 16 independent loads — compiler issues all before the first use.
    uint2 v[4][4];
    #pragma unroll
    for (int r = 0; r < 4; ++r)
        #pragma unroll
        for (int q = 0; q < 4; ++q)
            v[r][q] = f2[(ry[r] + cx[q]) * FC4 + c];

    // Bilinear per sample; max over the 2x2 pool window.
    // sample(dy,dx): rows (2dy, 2dy+1), cols (2dx, 2dx+1); weights wy[dy], wx[dx]
    const float wys[2] = { wyA, wyB };
    const float wxs[2] = { wxL, wxR };
    nat4 m = (nat4)(-INFINITY);
    #pragma unroll
    for (int dy = 0; dy < 2; ++dy) {
        #pragma unroll
        for (int dx = 0; dx < 2; ++dx) {
            const nat4 tl = bf2f(v[2 * dy    ][2 * dx]);
            const nat4 tr = bf2f(v[2 * dy    ][2 * dx + 1]);
            const nat4 bl = bf2f(v[2 * dy + 1][2 * dx]);
            const nat4 br = bf2f(v[2 * dy + 1][2 * dx + 1]);
            const nat4 s = lerp4(lerp4(tl, tr, wxs[dx]),
                                 lerp4(bl, br, wxs[dx]), wys[dy]);
            m = max4(m, s);
        }
    }

    // One contiguous NT dwordx4 store (write-once output stays out of L2).
    nat4* __restrict__ o4 = reinterpret_cast<nat4*>(out)
                          + (size_t)(n * NCELL + cell) * FC4 + c;
    __builtin_nontemporal_store(m, o4);
}

// Fallback (ws too small): same structure straight from fp32 features.
__global__ __launch_bounds__(64) void roi_pool_f32_kernel(
    const float* __restrict__ feat,
    const float* __restrict__ boxes,
    float* __restrict__ out)
{
    const int j = blockIdx.x & 7;
    const int k = blockIdx.x >> 3;
    const int n = j + 8 * (k / BPB);
    if (n >= NBOX) return;
    const int rem  = k % BPB;
    const int cell = rem >> 2;
    const int cq   = rem & 3;
    const int py   = cell / PO;
    const int px   = cell - py * PO;
    const int c    = cq * 64 + threadIdx.x;

    const float by1 = boxes[n * 4 + 0];
    const float bx1 = boxes[n * 4 + 1];
    const float by2 = boxes[n * 4 + 2];
    const float bx2 = boxes[n * 4 + 3];
    const float stepy = (by2 - by1) * (49.0f / 13.0f);
    const float stepx = (bx2 - bx1) * (49.0f / 13.0f);
    const float basey = by1 * 49.0f;
    const float basex = bx1 * 49.0f;
    const float ysA = basey + (float)(2 * py) * stepy;
    const float ysB = ysA + stepy;
    const float xsL = basex + (float)(2 * px) * stepx;
    const float xsR = xsL + stepx;
    const float fyA = floorf(ysA); const float wyA = ysA - fyA;
    const float fyB = floorf(ysB); const float wyB = ysB - fyB;
    const float fxL = floorf(xsL); const float wxL = xsL - fxL;
    const float fxR = floorf(xsR); const float wxR = xsR - fxR;
    const int y0A = min(max((int)fyA, 0), FH - 1); const int y1A = min(y0A + 1, FH - 1);
    const int y0B = min(max((int)fyB, 0), FH - 1); const int y1B = min(y0B + 1, FH - 1);
    const int x0L = min(max((int)fxL, 0), FW - 1); const int x1L = min(x0L + 1, FW - 1);
    const int x0R = min(max((int)fxR, 0), FW - 1); const int x1R = min(x0R + 1, FW - 1);

    const nat4* __restrict__ f4 = reinterpret_cast<const nat4*>(feat);
    const int ry[4] = { y0A * FW, y1A * FW, y0B * FW, y1B * FW };
    const int cx[4] = { x0L, x1L, x0R, x1R };

    nat4 v[4][4];
    #pragma unroll
    for (int r = 0; r < 4; ++r)
        #pragma unroll
        for (int q = 0; q < 4; ++q)
            v[r][q] = f4[(ry[r] + cx[q]) * FC4 + c];

    const float wys[2] = { wyA, wyB };
    const float wxs[2] = { wxL, wxR };
    nat4 m = (nat4)(-INFINITY);
    #pragma unroll
    for (int dy = 0; dy < 2; ++dy) {
        #pragma unroll
        for (int dx = 0; dx < 2; ++dx) {
            const nat4 s = lerp4(
                lerp4(v[2 * dy][2 * dx], v[2 * dy][2 * dx + 1], wxs[dx]),
                lerp4(v[2 * dy + 1][2 * dx], v[2 * dy + 1][2 * dx + 1], wxs[dx]),
                wys[dy]);
            m = max4(m, s);
        }
    }

    nat4* __restrict__ o4 = reinterpret_cast<nat4*>(out)
                          + (size_t)(n * NCELL + cell) * FC4 + c;
    __builtin_nontemporal_store(m, o4);
}

extern "C" void kernel_launch(void* const* d_in, const int* in_sizes, int n_in,
                              void* d_out, int out_size, void* d_ws, size_t ws_size,
                              hipStream_t stream) {
    const float* feat  = (const float*)d_in[0];  // (1,50,50,1024)
    const float* boxes = (const float*)d_in[1];  // (1,300,4)
    float* out = (float*)d_out;                  // (1,300,7,7,1024)

    // 8 XCD slots x ceil(300/8)=38 boxes x 49 cells x 4 channel-quarters
    dim3 grid(8 * 38 * BPB);   // 59,584 single-wave blocks
    dim3 block(64);

    if (ws_size >= (size_t)BF16_BYTES) {
        unsigned* wsb = (unsigned*)d_ws;
        cvt_kernel<<<dim3(NPIX / 4 / 256), dim3(256), 0, stream>>>(feat, wsb);
        roi_pool_bf16_kernel<<<grid, block, 0, stream>>>(wsb, boxes, out);
    } else {
        roi_pool_f32_kernel<<<grid, block, 0, stream>>>(feat, boxes, out);
    }
}

// Round 7
// 98.766 us; speedup vs baseline: 1.0451x; 1.0451x over previous
//
#include <hip/hip_runtime.h>
#include <math.h>

// features: (1,50,50,1024) fp32 NHWC; boxes: (1,300,4) [y1,x1,y2,x2] in [0,1]
// CROP=14, POOL_K=2 -> out (1,300,7,7,1024) fp32
#define FH 50
#define FW 50
#define FC 1024
#define FC4 256        // float4s per pixel (fp32) == uint2s per pixel (bf16)
#define NBOX 300
#define PO 7
#define CHQ 4          // channel quarters (64 thr x 4 ch = 256 ch)
#define NPIX (FH * FW * FC)      // 2,560,000 elements
#define BF16_BYTES (NPIX * 2)    // 5,242,880

typedef float nat4 __attribute__((ext_vector_type(4)));

__device__ __forceinline__ nat4 lerp4(nat4 a, nat4 b, float w) {
    return a + (b - a) * w;
}
__device__ __forceinline__ nat4 max4(nat4 a, nat4 b) {
    nat4 r;
    r.x = fmaxf(a.x, b.x);
    r.y = fmaxf(a.y, b.y);
    r.z = fmaxf(a.z, b.z);
    r.w = fmaxf(a.w, b.w);
    return r;
}
// unpack 4 bf16 channels (packed little-endian in uint2) to f32
__device__ __forceinline__ nat4 bf2f(uint2 u) {
    nat4 r;
    r.x = __uint_as_float(u.x << 16);
    r.y = __uint_as_float(u.x & 0xffff0000u);
    r.z = __uint_as_float(u.y << 16);
    r.w = __uint_as_float(u.y & 0xffff0000u);
    return r;
}
__device__ __forceinline__ unsigned bfpack(float a, float b) {  // RNE to bf16
    unsigned ua = __float_as_uint(a);
    unsigned ub = __float_as_uint(b);
    ua += 0x7fffu + ((ua >> 16) & 1u);
    ub += 0x7fffu + ((ub >> 16) & 1u);
    return (ua >> 16) | (ub & 0xffff0000u);
}

// Pass 1: fp32 features -> bf16 in workspace (15 MB traffic, ~3 us).
__global__ __launch_bounds__(256) void cvt_kernel(
    const float* __restrict__ feat, unsigned* __restrict__ ws)
{
    const int i = blockIdx.x * 256 + threadIdx.x;   // float4 index, 640,000 total
    const float4 v = reinterpret_cast<const float4*>(feat)[i];
    uint2 w;
    w.x = bfpack(v.x, v.y);
    w.y = bfpack(v.z, v.w);
    reinterpret_cast<uint2*>(ws)[i] = w;
}

// Pass 2: one SINGLE-WAVE block per (box, pooled row, channel-quarter).
// Rolling 4x2 bf16 column cache (R5's ~halved byte count) PLUS a 1-column
// software prefetch: loads for column ix+1 are issued before computing
// sample ix, so the vmcnt wait for each round is overlapped by one full
// compute phase. 8512 single-wave blocks keep TLP high (R4's lesson).
__global__ __launch_bounds__(64) void roi_pool_bf16_kernel(
    const unsigned* __restrict__ ws,   // bf16 features (50,50,1024)
    const float* __restrict__ boxes,   // (300,4)
    float* __restrict__ out)           // (300,7,7,1024)
{
    const int j = blockIdx.x & 7;              // XCD slot
    const int k = blockIdx.x >> 3;
    const int n = j + 8 * (k / (PO * CHQ));    // box->XCD affinity
    if (n >= NBOX) return;
    const int r  = k % (PO * CHQ);
    const int py = r >> 2;                     // pooled row 0..6
    const int cq = r & 3;                      // channel quarter 0..3
    const int c  = cq * 64 + threadIdx.x;      // uint2 index in pixel, 0..255

    const float by1 = boxes[n * 4 + 0];
    const float bx1 = boxes[n * 4 + 1];
    const float by2 = boxes[n * 4 + 2];
    const float bx2 = boxes[n * 4 + 3];

    const float stepy = (by2 - by1) * (49.0f / 13.0f);
    const float stepx = (bx2 - bx1) * (49.0f / 13.0f);
    const float basey = by1 * 49.0f;
    const float basex = bx1 * 49.0f;

    const float ysA = basey + (float)(2 * py) * stepy;
    const float ysB = ysA + stepy;
    const float fA = floorf(ysA); const float wyA = ysA - fA;
    const float fB = floorf(ysB); const float wyB = ysB - fB;
    const int y0A = min(max((int)fA, 0), FH - 1); const int y1A = min(y0A + 1, FH - 1);
    const int y0B = min(max((int)fB, 0), FH - 1); const int y1B = min(y0B + 1, FH - 1);

    const uint2* __restrict__ f2 = reinterpret_cast<const uint2*>(ws);
    const int r0 = y0A * FW, r1 = y1A * FW, r2 = y0B * FW, r3 = y1B * FW;

    // cur: bf16 pixels at cols (cc, min(cc+1,49)) for the 4 rows.
    uint2 c00, c01, c10, c11, c20, c21, c30, c31;   // [row][col]
    uint2 n00, n01, n10, n11, n20, n21, n30, n31;   // incoming

    // Prologue: load sample-0 columns (the one unavoidable stall).
    int cc;
    {
        const float xf = floorf(basex);
        cc = min(max((int)xf, 0), FW - 1);
        const int x1 = min(cc + 1, FW - 1);
        c00 = f2[(r0 + cc) * FC4 + c];  c01 = f2[(r0 + x1) * FC4 + c];
        c10 = f2[(r1 + cc) * FC4 + c];  c11 = f2[(r1 + x1) * FC4 + c];
        c20 = f2[(r2 + cc) * FC4 + c];  c21 = f2[(r2 + x1) * FC4 + c];
        c30 = f2[(r3 + cc) * FC4 + c];  c31 = f2[(r3 + x1) * FC4 + c];
    }

    nat4 m = (nat4)(-INFINITY);
    nat4* __restrict__ obase =
        reinterpret_cast<nat4*>(out) + (size_t)(n * (PO * PO) + py * PO) * FC4 + c;

    for (int ix = 0; ix < 2 * PO; ++ix) {
        // ---- Prefetch: issue loads for column ix+1 (no load dependence) ----
        int d = 0;
        if (ix < 2 * PO - 1) {
            const float xsn = basex + (float)(ix + 1) * stepx;
            const int nx0 = min(max((int)floorf(xsn), 0), FW - 1);
            const int nx1 = min(nx0 + 1, FW - 1);
            d = nx0 - cc;
            if (d == 1) {
                n01 = f2[(r0 + nx1) * FC4 + c];
                n11 = f2[(r1 + nx1) * FC4 + c];
                n21 = f2[(r2 + nx1) * FC4 + c];
                n31 = f2[(r3 + nx1) * FC4 + c];
            } else if (d >= 2) {
                n00 = f2[(r0 + nx0) * FC4 + c];  n01 = f2[(r0 + nx1) * FC4 + c];
                n10 = f2[(r1 + nx0) * FC4 + c];  n11 = f2[(r1 + nx1) * FC4 + c];
                n20 = f2[(r2 + nx0) * FC4 + c];  n21 = f2[(r2 + nx1) * FC4 + c];
                n30 = f2[(r3 + nx0) * FC4 + c];  n31 = f2[(r3 + nx1) * FC4 + c];
            }
            cc = nx0;
        }

        // ---- Compute sample ix from current registers ----
        {
            const float xs = basex + (float)ix * stepx;
            const float wx = xs - floorf(xs);   // unclipped floor for the weight
            const nat4 vA = lerp4(lerp4(bf2f(c00), bf2f(c01), wx),
                                  lerp4(bf2f(c10), bf2f(c11), wx), wyA);
            const nat4 vB = lerp4(lerp4(bf2f(c20), bf2f(c21), wx),
                                  lerp4(bf2f(c30), bf2f(c31), wx), wyB);
            m = max4(m, max4(vA, vB));
        }

        if (ix & 1) {
            // write-once output: NT store keeps it out of L1/L2
            __builtin_nontemporal_store(m, obase + (ix >> 1) * FC4);
            m = (nat4)(-INFINITY);
        }

        // ---- Rotate incoming -> current (wave-uniform branches) ----
        if (ix < 2 * PO - 1) {
            if (d == 1) {
                c00 = c01; c10 = c11; c20 = c21; c30 = c31;
                c01 = n01; c11 = n11; c21 = n21; c31 = n31;
            } else if (d >= 2) {
                c00 = n00; c01 = n01; c10 = n10; c11 = n11;
                c20 = n20; c21 = n21; c30 = n30; c31 = n31;
            }
        }
    }
}

// Fallback (ws too small): R4's fp32 single-wave rolling-cache kernel.
__global__ __launch_bounds__(64) void roi_pool_f32_kernel(
    const float* __restrict__ feat,
    const float* __restrict__ boxes,
    float* __restrict__ out)
{
    const int j = blockIdx.x & 7;
    const int k = blockIdx.x >> 3;
    const int n = j + 8 * (k / (PO * CHQ));
    if (n >= NBOX) return;
    const int r  = k % (PO * CHQ);
    const int py = r >> 2;
    const int cq = r & 3;
    const int c4 = cq * 64 + threadIdx.x;

    const float by1 = boxes[n * 4 + 0];
    const float bx1 = boxes[n * 4 + 1];
    const float by2 = boxes[n * 4 + 2];
    const float bx2 = boxes[n * 4 + 3];
    const float stepy = (by2 - by1) * (49.0f / 13.0f);
    const float stepx = (bx2 - bx1) * (49.0f / 13.0f);
    const float basey = by1 * 49.0f;
    const float basex = bx1 * 49.0f;
    const float ysA = basey + (float)(2 * py) * stepy;
    const float ysB = ysA + stepy;
    const float fA = floorf(ysA); const float wyA = ysA - fA;
    const float fB = floorf(ysB); const float wyB = ysB - fB;
    const int y0A = min(max((int)fA, 0), FH - 1); const int y1A = min(y0A + 1, FH - 1);
    const int y0B = min(max((int)fB, 0), FH - 1); const int y1B = min(y0B + 1, FH - 1);

    const nat4* __restrict__ f4 = reinterpret_cast<const nat4*>(feat);
    const int rA0 = y0A * FW, rA1 = y1A * FW, rB0 = y0B * FW, rB1 = y1B * FW;

    int cc = -1000;
    nat4 A00, A01, A10, A11, B00, B01, B10, B11;
    A00 = A01 = A10 = A11 = B00 = B01 = B10 = B11 = (nat4)0.0f;
    nat4 m = (nat4)(-INFINITY);
    nat4* __restrict__ obase =
        reinterpret_cast<nat4*>(out) + (size_t)(n * (PO * PO) + py * PO) * FC4 + c4;

    for (int ix = 0; ix < 2 * PO; ++ix) {
        const float xs = basex + (float)ix * stepx;
        const float xf = floorf(xs);
        const float wx = xs - xf;
        int x0 = min(max((int)xf, 0), FW - 1);
        const int x1 = min(x0 + 1, FW - 1);
        if (x0 != cc) {
            if (x0 == cc + 1) {
                A00 = A01; A10 = A11; B00 = B01; B10 = B11;
                A01 = f4[(rA0 + x1) * FC4 + c4];
                A11 = f4[(rA1 + x1) * FC4 + c4];
                B01 = f4[(rB0 + x1) * FC4 + c4];
                B11 = f4[(rB1 + x1) * FC4 + c4];
            } else {
                A00 = f4[(rA0 + x0) * FC4 + c4];
                A01 = f4[(rA0 + x1) * FC4 + c4];
                A10 = f4[(rA1 + x0) * FC4 + c4];
                A11 = f4[(rA1 + x1) * FC4 + c4];
                B00 = f4[(rB0 + x0) * FC4 + c4];
                B01 = f4[(rB0 + x1) * FC4 + c4];
                B10 = f4[(rB1 + x0) * FC4 + c4];
                B11 = f4[(rB1 + x1) * FC4 + c4];
            }
            cc = x0;
        }
        const nat4 vA = lerp4(lerp4(A00, A01, wx), lerp4(A10, A11, wx), wyA);
        const nat4 vB = lerp4(lerp4(B00, B01, wx), lerp4(B10, B11, wx), wyB);
        m = max4(m, max4(vA, vB));
        if (ix & 1) {
            __builtin_nontemporal_store(m, obase + (ix >> 1) * FC4);
            m = (nat4)(-INFINITY);
        }
    }
}

extern "C" void kernel_launch(void* const* d_in, const int* in_sizes, int n_in,
                              void* d_out, int out_size, void* d_ws, size_t ws_size,
                              hipStream_t stream) {
    const float* feat  = (const float*)d_in[0];  // (1,50,50,1024)
    const float* boxes = (const float*)d_in[1];  // (1,300,4)
    float* out = (float*)d_out;                  // (1,300,7,7,1024)

    dim3 grid(8 * 38 * PO * CHQ);   // 8512 single-wave blocks
    dim3 block(64);

    if (ws_size >= (size_t)BF16_BYTES) {
        unsigned* wsb = (unsigned*)d_ws;
        cvt_kernel<<<dim3(NPIX / 4 / 256), dim3(256), 0, stream>>>(feat, wsb);
        roi_pool_bf16_kernel<<<grid, block, 0, stream>>>(wsb, boxes, out);
    } else {
        roi_pool_f32_kernel<<<grid, block, 0, stream>>>(feat, boxes, out);
    }
}